// Round 6
// baseline (556.284 us; speedup 1.0000x reference)
//
#include <hip/hip_runtime.h>
#include <math.h>

// Problem constants (fixed by the reference).
#define BQ   16384
#define FQ   64
#define NBQ  64
#define HD   128
#define FG   4       // feature groups
#define FPG  16      // features per group
#define MT   128     // batch rows per block
#define NT   512     // threads (8 waves)

typedef __attribute__((ext_vector_type(8))) short s16x8;   // 8 bf16 (4 VGPRs)
typedef __attribute__((ext_vector_type(4))) float f32x4;   // MFMA C/D

// round-to-nearest-even fp32 -> bf16 (weight prep only)
__device__ __forceinline__ unsigned short f2bf(float x) {
    unsigned int u = __float_as_uint(x);
    return (unsigned short)((u + 0x7FFFu + ((u >> 16) & 1u)) >> 16);
}
// truncation fp32 -> bf16 (activations)
__device__ __forceinline__ unsigned short bftr(float x) {
    return (unsigned short)(__float_as_uint(x) >> 16);
}

__device__ __forceinline__ float softplus_stable(float v) {
    return (v > 0.0f) ? (v + log1pf(expf(-v))) : log1pf(expf(v));
}

// tanh-form gelu as sigmoid: gelu(v) = v / (1 + exp(-(1.5957691 v + 0.07135481 v^3)))
__device__ __forceinline__ f32x4 gelu4(f32x4 v) {
    const f32x4 v2 = v * v;
    const f32x4 tt = v2 * (-0.07135481f) + (-1.5957691f);
    const f32x4 s  = v * tt;
    f32x4 r;
    r[0] = __fdividef(v[0], 1.0f + __expf(s[0]));
    r[1] = __fdividef(v[1], 1.0f + __expf(s[1]));
    r[2] = __fdividef(v[2], 1.0f + __expf(s[2]));
    r[3] = __fdividef(v[3], 1.0f + __expf(s[3]));
    return r;
}

// sum across the 16 lanes of a DPP row — no LDS ops.
__device__ __forceinline__ float dppsum16(float x) {
    int t;
    t = __builtin_amdgcn_update_dpp(0, __float_as_int(x), 0xB1,  0xF, 0xF, true); // quad_perm [1,0,3,2]
    x += __int_as_float(t);
    t = __builtin_amdgcn_update_dpp(0, __float_as_int(x), 0x4E,  0xF, 0xF, true); // quad_perm [2,3,0,1]
    x += __int_as_float(t);
    t = __builtin_amdgcn_update_dpp(0, __float_as_int(x), 0x125, 0xF, 0xF, true); // row_ror:4
    x += __int_as_float(t);
    t = __builtin_amdgcn_update_dpp(0, __float_as_int(x), 0x129, 0xF, 0xF, true); // row_ror:8
    x += __int_as_float(t);
    return x;
}

// async 16B global->LDS
__device__ __forceinline__ void load16_lds(const unsigned short* g, unsigned short* l) {
    __builtin_amdgcn_global_load_lds(
        (const __attribute__((address_space(1))) unsigned int*)(uintptr_t)g,
        (__attribute__((address_space(3))) unsigned int*)(uintptr_t)l,
        16, 0, 0);
}

// h1g LDS addressing: stride 128 shorts, XOR swizzle to spread banks.
__device__ __forceinline__ int hofs(int row, int col) {
    return row * 128 + (col ^ (((row >> 2) & 3) << 4));
}

// ---------------- fused prep ----------------
// blocks 0..255: LDS-tiled weight convert+swizzle (64 W1 | 64 Wr | 128 W2-halves)
// block 256: softmax + rbf coeffs + folded head bias
// blocks 257..288: LN param pack
__global__ void __launch_bounds__(256) prep_all(
    const float* __restrict__ att, const float* __restrict__ log_widths,
    const float* __restrict__ centers, const float* __restrict__ br,
    const float* __restrict__ bias,
    const float* __restrict__ W1, const float* __restrict__ Wr, const float* __restrict__ W2,
    const float* __restrict__ b1, const float* __restrict__ g1, const float* __restrict__ be1,
    const float* __restrict__ b2, const float* __restrict__ g2, const float* __restrict__ be2,
    unsigned short* __restrict__ W1s, unsigned short* __restrict__ Wrs,
    unsigned short* __restrict__ W2s,
    float* __restrict__ wsoft, float* __restrict__ crw2, float* __restrict__ rbias,
    float* __restrict__ Pk)
{
    const int bid = blockIdx.x;
    const int t   = threadIdx.x;

    if (bid < 256) {
        // ---- tiled swizzle: 64 K-rows x 128 cols fp32 -> MFMA B-frag bf16 ----
        __shared__ unsigned int tile32[4096];   // bf16 tile [64][128] as u32 pairs
        const float* src; unsigned short* dst; int KB, kbase;
        if (bid < 64)       { src = W1 + (size_t)bid * 8192;        dst = W1s + (size_t)bid * 8192;        KB = 8;  kbase = 0; }
        else if (bid < 128) { src = Wr + (size_t)(bid - 64) * 8192; dst = Wrs + (size_t)(bid - 64) * 8192; KB = 8;  kbase = 0; }
        else {
            const int u = bid - 128, f = u >> 1, half = u & 1;
            src = W2 + ((size_t)f * 128 + half * 64) * 128;
            dst = W2s + (size_t)f * 16384;
            KB = 16; kbase = half * 8;
        }
        const float4* src4 = (const float4*)src;
#pragma unroll
        for (int i = 0; i < 8; ++i) {
            const int idx = t + i * 256;            // 2048 float4
            const float4 v = src4[idx];
            const unsigned int u0 = (unsigned int)f2bf(v.x) | ((unsigned int)f2bf(v.y) << 16);
            const unsigned int u1 = (unsigned int)f2bf(v.z) | ((unsigned int)f2bf(v.w) << 16);
            tile32[idx * 2]     = u0;
            tile32[idx * 2 + 1] = u1;
        }
        __syncthreads();
        const unsigned short* tile16 = (const unsigned short*)tile32;
#pragma unroll
        for (int i = 0; i < 4; ++i) {
            const int u  = t + i * 256;             // 1024 frag units
            const int nn = u & 15;
            const int kb = (u >> 4) & 7;
            const int nt = u >> 7;
            s16x8 o;
#pragma unroll
            for (int j = 0; j < 8; ++j)
                o[j] = (short)tile16[(kb * 8 + j) * 128 + nt * 16 + nn];
            *(s16x8*)(dst + ((size_t)((nt * KB + kbase + kb) * 16 + nn)) * 8) = o;
        }
    } else if (bid == 256) {
        // ---- softmax + rbf coeffs + folded head bias ----
        __shared__ float ws[64];
        if (t < 64) {
            float v = att[t];
            float m = v;
#pragma unroll
            for (int s = 32; s >= 1; s >>= 1) m = fmaxf(m, __shfl_xor(m, s, 64));
            float e = expf(v - m);
            float ssum = e;
#pragma unroll
            for (int s = 32; s >= 1; s >>= 1) ssum += __shfl_xor(ssum, s, 64);
            const float w = e / ssum;
            ws[t] = w;
            wsoft[t] = w;
        }
        __syncthreads();
        for (int i = t; i < FQ * NBQ; i += 256) {
            float lw = fminf(fmaxf(log_widths[i], -5.0f), 5.0f);
            const float rw = 1.0f / (expf(lw) + 0.1f);
            ((float2*)crw2)[i] = make_float2(rw, -centers[i] * rw);
        }
        if (t < HD) {
            float s = bias[t];
            for (int f = 0; f < FQ; ++f) s += 0.1f * ws[f] * br[f * HD + t];
            rbias[t] = s;
        }
    } else {
        // ---- pack LN params: Pk[(f*128+c)*8] = {b1,g1,be1,0, b2,g2,be2,0} ----
        const int id = (bid - 257) * 256 + t;
        if (id < FQ * HD) {
            ((float4*)Pk)[id * 2]     = make_float4(b1[id], g1[id], be1[id], 0.0f);
            ((float4*)Pk)[id * 2 + 1] = make_float4(b2[id], g2[id], be2[id], 0.0f);
        }
    }
}

// ---------------- fused MFMA NAM body ----------------
// grid 512 = 4 fgroups x 128 row-tiles (M=128). 512 threads = 8 waves, 16 rows/wave.
// Two 32KB LDS regions rotate roles each iteration:
//   P: W1r(f) [start..B2] then W2(f) [B2..GEMM2 end]
//   Q: h1g(f) [LN1..A2 load] then W1r(f+1) DMA [B4.. next B1]
// Every DMA has >=1.5K cycles of cover -> barriers are skew-only.
__global__ void __launch_bounds__(NT, 4) nam_main(
    const float* __restrict__ crw2,
    const float* __restrict__ x,
    const unsigned short* __restrict__ W1s,
    const unsigned short* __restrict__ Wrs,
    const unsigned short* __restrict__ W2s,
    const float* __restrict__ Pk,
    const float* __restrict__ wsoft,
    float* __restrict__ aggP)
{
    __shared__ __align__(16) unsigned short lds[32768];   // 64 KB total

    const int t    = threadIdx.x;
    const int ln   = t & 63;
    const int wv   = t >> 6;        // wave 0..7
    const int n    = ln & 15;
    const int q    = ln >> 4;
    const int wrow = wv * 16;
    const int fg   = blockIdx.x & 3;
    const int rb   = blockIdx.x >> 2;     // 0..127
    const int b0   = rb * MT;

    f32x4 acc[8];
#pragma unroll
    for (int nt = 0; nt < 8; ++nt) acc[nt] = f32x4{0.f, 0.f, 0.f, 0.f};

    // ---- preamble: DMA first feature's W1+Wr into region 0 ----
    {
        const int f0 = fg * FPG + (rb & (FPG - 1));
        const unsigned short* gw1 = W1s + (size_t)f0 * 8192;
        const unsigned short* gwr = Wrs + (size_t)f0 * 8192;
#pragma unroll
        for (int i = 0; i < 4; ++i) {
            const int chunk = i * 8 + wv;
            const unsigned short* src = (chunk < 16) ? (gw1 + chunk * 512)
                                                     : (gwr + (chunk - 16) * 512);
            load16_lds(src + ln * 8, lds + chunk * 512);
        }
    }

    for (int ff = 0; ff < FPG; ++ff) {
        const int f = fg * FPG + ((ff + rb) & (FPG - 1));   // decorrelated order
        unsigned short* W = lds + ((ff & 1) ? 16384 : 0);   // W1r then W2
        unsigned short* H = lds + ((ff & 1) ? 0 : 16384);   // h1g then next W1r

        // ---- rbf A-fragments directly in registers ----
        s16x8 a0, a1;
        {
            float xv = x[(size_t)(b0 + wrow + n) * FQ + f];
            xv = fminf(fmaxf(xv, -10.0f), 10.0f);
            const float4* c4 = ((const float4*)crw2) + f * 32;
            unsigned int p[8];
#pragma unroll
            for (int h = 0; h < 2; ++h) {
#pragma unroll
                for (int i = 0; i < 4; ++i) {
                    const float4 cc = c4[h * 16 + q * 4 + i];   // {rw,nc, rw,nc}
                    const float d0 = fmaf(xv, cc.x, cc.y);
                    const float d1 = fmaf(xv, cc.z, cc.w);
                    const float e0 = __expf(-0.5f * d0 * d0);
                    const float e1 = __expf(-0.5f * d1 * d1);
                    p[h * 4 + i] = __builtin_amdgcn_perm(__float_as_uint(e1),
                                                         __float_as_uint(e0), 0x07060302u);
                }
            }
            int4 pa = make_int4(p[0], p[1], p[2], p[3]);
            int4 pb = make_int4(p[4], p[5], p[6], p[7]);
            a0 = *(s16x8*)&pa;
            a1 = *(s16x8*)&pb;
        }
        const float wf   = wsoft[f];
        const float wf01 = 0.1f * wf;
        __syncthreads();   // B1: W1r(f) ready in W (DMA in flight ~2.5K cyc)

        // ---- GEMM1 (hc) + GEMMr folded straight into acc ----
        f32x4 hc[8];
#pragma unroll
        for (int nt = 0; nt < 8; ++nt) {
            const s16x8 bA = *(const s16x8*)&W[(nt * 8 + 0) * 128 + ln * 8];
            const s16x8 bB = *(const s16x8*)&W[(nt * 8 + 4) * 128 + ln * 8];
            f32x4 z = f32x4{0.f, 0.f, 0.f, 0.f};
            z = __builtin_amdgcn_mfma_f32_16x16x32_bf16(a0, bA, z, 0, 0, 0);
            z = __builtin_amdgcn_mfma_f32_16x16x32_bf16(a1, bB, z, 0, 0, 0);
            hc[nt] = z;
            const s16x8 cA = *(const s16x8*)&W[8192 + (nt * 8 + 0) * 128 + ln * 8];
            const s16x8 cB = *(const s16x8*)&W[8192 + (nt * 8 + 4) * 128 + ln * 8];
            f32x4 y = f32x4{0.f, 0.f, 0.f, 0.f};
            y = __builtin_amdgcn_mfma_f32_16x16x32_bf16(a0, cA, y, 0, 0, 0);
            y = __builtin_amdgcn_mfma_f32_16x16x32_bf16(a1, cB, y, 0, 0, 0);
            acc[nt] = y * wf01 + acc[nt];
        }
        __syncthreads();   // B2: W free (skew only)

        // ---- stage W2(f) -> W, covered by LN1 below ----
        {
            const unsigned short* gw2 = W2s + (size_t)f * 16384;
#pragma unroll
            for (int i = 0; i < 4; ++i) {
                const int chunk = i * 8 + wv;
                load16_lds(gw2 + chunk * 512 + ln * 8, W + chunk * 512);
            }
        }

        // ---- LN1 (+b1), DPP reduce, gelu, h1g -> H ----
        const size_t pkb = ((size_t)f * HD + n) * 8;
        f32x4 sm = {0.f, 0.f, 0.f, 0.f}, sq = {0.f, 0.f, 0.f, 0.f};
#pragma unroll
        for (int nt = 0; nt < 8; ++nt) {
            const float4 pA = *(const float4*)(Pk + pkb + nt * 128);
            const f32x4 v = hc[nt] + pA.x;
            hc[nt] = v; sm += v; sq += v * v;
        }
        f32x4 mu4, rs4;
#pragma unroll
        for (int i = 0; i < 4; ++i) {
            const float s  = dppsum16(sm[i]);
            const float qq = dppsum16(sq[i]);
            mu4[i] = s * (1.0f / 128.0f);
            const float var = qq * (1.0f / 128.0f) - mu4[i] * mu4[i];
            rs4[i] = rsqrtf(var + 1e-5f);
        }
#pragma unroll
        for (int nt = 0; nt < 8; ++nt) {
            const float4 pA = *(const float4*)(Pk + pkb + nt * 128);
            const f32x4 sg = rs4 * pA.y;
            const f32x4 c1 = -mu4 * sg + pA.z;
            const f32x4 z  = gelu4(hc[nt] * sg + c1);
#pragma unroll
            for (int i = 0; i < 4; ++i)
                H[hofs(wrow + q * 4 + i, nt * 16 + n)] = bftr(z[i]);
        }
        __syncthreads();   // B3: W2 drained (LN1 cover) + h1g visible

        // ---- lift A2 fragments, then free H for the next W1r DMA ----
        s16x8 A2[4];
#pragma unroll
        for (int c = 0; c < 4; ++c)
            A2[c] = *(const s16x8*)&H[hofs(wrow + n, c * 32 + q * 8)];
        __syncthreads();   // B4: H free (skew only; lgkm drained by barrier)

        if (ff + 1 < FPG) {
            const int f2 = fg * FPG + ((ff + 1 + rb) & (FPG - 1));
            const unsigned short* gw1 = W1s + (size_t)f2 * 8192;
            const unsigned short* gwr = Wrs + (size_t)f2 * 8192;
#pragma unroll
            for (int i = 0; i < 4; ++i) {
                const int chunk = i * 8 + wv;
                const unsigned short* src = (chunk < 16) ? (gw1 + chunk * 512)
                                                         : (gwr + (chunk - 16) * 512);
                load16_lds(src + ln * 8, H + chunk * 512);
            }
        }

        // ---- GEMM2: A = h1g frags (K=128), B from W; output reuses hc ----
#pragma unroll
        for (int nt = 0; nt < 8; ++nt) {
            f32x4 z = f32x4{0.f, 0.f, 0.f, 0.f};
#pragma unroll
            for (int c = 0; c < 4; ++c) {
                const s16x8 bF = *(const s16x8*)&W[(nt * 16 + c * 4) * 128 + ln * 8];
                z = __builtin_amdgcn_mfma_f32_16x16x32_bf16(A2[c], bF, z, 0, 0, 0);
            }
            hc[nt] = z;
        }

        // ---- LN2 (+b2), gelu, attention weight into acc ----
        sm = f32x4{0.f, 0.f, 0.f, 0.f}; sq = f32x4{0.f, 0.f, 0.f, 0.f};
#pragma unroll
        for (int nt = 0; nt < 8; ++nt) {
            const float4 pB = *(const float4*)(Pk + pkb + nt * 128 + 4);
            const f32x4 v = hc[nt] + pB.x;
            hc[nt] = v; sm += v; sq += v * v;
        }
#pragma unroll
        for (int i = 0; i < 4; ++i) {
            const float s  = dppsum16(sm[i]);
            const float qq = dppsum16(sq[i]);
            mu4[i] = s * (1.0f / 128.0f);
            const float var = qq * (1.0f / 128.0f) - mu4[i] * mu4[i];
            rs4[i] = rsqrtf(var + 1e-5f);
        }
#pragma unroll
        for (int nt = 0; nt < 8; ++nt) {
            const float4 pB = *(const float4*)(Pk + pkb + nt * 128 + 4);
            const f32x4 sg = rs4 * pB.y;
            const f32x4 c1 = -mu4 * sg + pB.z;
            acc[nt] = gelu4(hc[nt] * sg + c1) * wf + acc[nt];
        }
        // no end barrier: next iter's B1/B2 already order H-writes vs GEMM2 reads
    }

    // ---- epilogue: plain stores into this fgroup's partial (no atomics) ----
    float* ap = aggP + ((size_t)fg * BQ + b0 + wrow + q * 4) * HD + n;
#pragma unroll
    for (int nt = 0; nt < 8; ++nt) {
#pragma unroll
        for (int i = 0; i < 4; ++i) {
            ap[(size_t)i * HD + nt * 16] = acc[nt][i];
        }
    }
}

// ---------------- mixture-beta head: one wave per batch row ----------------
__global__ void __launch_bounds__(256) nam_head(
    const float* __restrict__ aggP, const float* __restrict__ rbias,
    const float* __restrict__ Wpi, const float* __restrict__ bpi,
    const float* __restrict__ Wa,  const float* __restrict__ ba,
    const float* __restrict__ Wb,  const float* __restrict__ bb,
    float* __restrict__ out)
{
    const int gid  = blockIdx.x * blockDim.x + threadIdx.x;
    const int row  = gid >> 6;
    const int lane = threadIdx.x & 63;
    if (row >= BQ) return;

    const float2 p0 = ((const float2*)(aggP + (size_t)row * HD))[lane];
    const float2 p1 = ((const float2*)(aggP + ((size_t)BQ + row) * HD))[lane];
    const float2 p2 = ((const float2*)(aggP + ((size_t)2 * BQ + row) * HD))[lane];
    const float2 p3 = ((const float2*)(aggP + ((size_t)3 * BQ + row) * HD))[lane];
    const float2 rb = ((const float2*)rbias)[lane];
    const float ax = p0.x + p1.x + p2.x + p3.x + rb.x;
    const float ay = p0.y + p1.y + p2.y + p3.y + rb.y;

    const float2* wp = (const float2*)Wpi;
    const float2* wa = (const float2*)Wa;
    const float2* wb = (const float2*)Wb;
    const float2 p01 = wp[lane * 3], p23 = wp[lane * 3 + 1], p45 = wp[lane * 3 + 2];
    const float2 a01 = wa[lane * 3], a23 = wa[lane * 3 + 1], a45 = wa[lane * 3 + 2];
    const float2 b01 = wb[lane * 3], b23 = wb[lane * 3 + 1], b45 = wb[lane * 3 + 2];

    float ppi0 = ax * p01.x + ay * p23.y;
    float ppi1 = ax * p01.y + ay * p45.x;
    float ppi2 = ax * p23.x + ay * p45.y;
    float pa0  = ax * a01.x + ay * a23.y;
    float pa1  = ax * a01.y + ay * a45.x;
    float pa2  = ax * a23.x + ay * a45.y;
    float pb0  = ax * b01.x + ay * b23.y;
    float pb1  = ax * b01.y + ay * b45.x;
    float pb2  = ax * b23.x + ay * b45.y;

#pragma unroll
    for (int s = 32; s >= 1; s >>= 1) {
        ppi0 += __shfl_xor(ppi0, s, 64);
        ppi1 += __shfl_xor(ppi1, s, 64);
        ppi2 += __shfl_xor(ppi2, s, 64);
        pa0  += __shfl_xor(pa0,  s, 64);
        pa1  += __shfl_xor(pa1,  s, 64);
        pa2  += __shfl_xor(pa2,  s, 64);
        pb0  += __shfl_xor(pb0,  s, 64);
        pb1  += __shfl_xor(pb1,  s, 64);
        pb2  += __shfl_xor(pb2,  s, 64);
    }

    if (lane == 0) {
        const float z0 = ppi0 + bpi[0], z1 = ppi1 + bpi[1], z2 = ppi2 + bpi[2];
        const float mz = fmaxf(z0, fmaxf(z1, z2));
        const float e0 = expf(z0 - mz), e1 = expf(z1 - mz), e2 = expf(z2 - mz);
        const float es = e0 + e1 + e2;

        const float al0 = fminf(fmaxf(softplus_stable(pa0 + ba[0]) + 1.01f, 1.01f), 100.0f);
        const float al1 = fminf(fmaxf(softplus_stable(pa1 + ba[1]) + 1.01f, 1.01f), 100.0f);
        const float al2 = fminf(fmaxf(softplus_stable(pa2 + ba[2]) + 1.01f, 1.01f), 100.0f);
        const float bt0 = fminf(fmaxf(softplus_stable(pb0 + bb[0]) + 1.01f, 1.01f), 100.0f);
        const float bt1 = fminf(fmaxf(softplus_stable(pb1 + bb[1]) + 1.01f, 1.01f), 100.0f);
        const float bt2 = fminf(fmaxf(softplus_stable(pb2 + bb[2]) + 1.01f, 1.01f), 100.0f);

        const float pred = (e0 * (al0 / (al0 + bt0))
                          + e1 * (al1 / (al1 + bt1))
                          + e2 * (al2 / (al2 + bt2))) / es;
        out[row] = fminf(fmaxf(pred, 0.001f), 0.999f);
    }
}

extern "C" void kernel_launch(void* const* d_in, const int* in_sizes, int n_in,
                              void* d_out, int out_size, void* d_ws, size_t ws_size,
                              hipStream_t stream) {
    const float* x          = (const float*)d_in[0];
    const float* centers    = (const float*)d_in[1];
    const float* log_widths = (const float*)d_in[2];
    const float* W1   = (const float*)d_in[3];
    const float* b1   = (const float*)d_in[4];
    const float* g1   = (const float*)d_in[5];
    const float* be1  = (const float*)d_in[6];
    const float* W2   = (const float*)d_in[7];
    const float* b2   = (const float*)d_in[8];
    const float* g2   = (const float*)d_in[9];
    const float* be2  = (const float*)d_in[10];
    const float* Wr   = (const float*)d_in[11];
    const float* br   = (const float*)d_in[12];
    const float* att  = (const float*)d_in[13];
    const float* bias = (const float*)d_in[14];
    const float* Wpi  = (const float*)d_in[15];
    const float* bpi  = (const float*)d_in[16];
    const float* Wa   = (const float*)d_in[17];
    const float* ba   = (const float*)d_in[18];
    const float* Wb   = (const float*)d_in[19];
    const float* bb   = (const float*)d_in[20];

    // ---- workspace layout (byte offsets, 16B-aligned; top ≈ 36.5 MB) ----
    char* ws = (char*)d_ws;
    float*          wsoft = (float*)(ws + 0);          //   256 B
    float*          rbias = (float*)(ws + 1024);       //   512 B
    float*          crw2  = (float*)(ws + 8192);       //  32 KB (float2[4096])
    float*          Pk    = (float*)(ws + 65536);      // 256 KB
    unsigned short* W1s   = (unsigned short*)(ws + 327680);    // 1 MB
    unsigned short* Wrs   = (unsigned short*)(ws + 1376256);   // 1 MB
    unsigned short* W2s   = (unsigned short*)(ws + 2424832);   // 2 MB
    float*          aggP  = (float*)(ws + 4521984);    //  32 MB (4 partials)

    prep_all<<<289, 256, 0, stream>>>(att, log_widths, centers, br, bias,
                                      W1, Wr, W2, b1, g1, be1, b2, g2, be2,
                                      W1s, Wrs, W2s, wsoft, crw2, rbias, Pk);

    nam_main<<<(BQ / MT) * FG, NT, 0, stream>>>(crw2, x, W1s, Wrs, W2s, Pk,
                                                wsoft, aggP);

    nam_head<<<BQ / 4, 256, 0, stream>>>(aggP, rbias, Wpi, bpi, Wa, ba, Wb, bb,
                                         (float*)d_out);
}

// Round 7
// 546.850 us; speedup vs baseline: 1.0173x; 1.0173x over previous
//
#include <hip/hip_runtime.h>
#include <math.h>

// Problem constants (fixed by the reference).
#define BQ   16384
#define FQ   64
#define NBQ  64
#define HD   128
#define FG   4       // feature groups
#define FPG  16      // features per group
#define MT   128     // batch rows per block
#define NT   512     // threads (8 waves)

typedef __attribute__((ext_vector_type(8))) short s16x8;   // 8 bf16 (4 VGPRs)
typedef __attribute__((ext_vector_type(4))) float f32x4;   // MFMA C/D

// round-to-nearest-even fp32 -> bf16 (weight prep only)
__device__ __forceinline__ unsigned short f2bf(float x) {
    unsigned int u = __float_as_uint(x);
    return (unsigned short)((u + 0x7FFFu + ((u >> 16) & 1u)) >> 16);
}
// truncation fp32 -> bf16 (activations)
__device__ __forceinline__ unsigned short bftr(float x) {
    return (unsigned short)(__float_as_uint(x) >> 16);
}

__device__ __forceinline__ float softplus_stable(float v) {
    return (v > 0.0f) ? (v + log1pf(expf(-v))) : log1pf(expf(v));
}

// tanh-form gelu as sigmoid: gelu(v) = v / (1 + exp(-(1.5957691 v + 0.07135481 v^3)))
__device__ __forceinline__ f32x4 gelu4(f32x4 v) {
    const f32x4 v2 = v * v;
    const f32x4 tt = v2 * (-0.07135481f) + (-1.5957691f);
    const f32x4 s  = v * tt;
    f32x4 r;
    r[0] = __fdividef(v[0], 1.0f + __expf(s[0]));
    r[1] = __fdividef(v[1], 1.0f + __expf(s[1]));
    r[2] = __fdividef(v[2], 1.0f + __expf(s[2]));
    r[3] = __fdividef(v[3], 1.0f + __expf(s[3]));
    return r;
}

// sum across the 16 lanes of a DPP row — no LDS ops.
__device__ __forceinline__ float dppsum16(float x) {
    int t;
    t = __builtin_amdgcn_update_dpp(0, __float_as_int(x), 0xB1,  0xF, 0xF, true); // quad_perm [1,0,3,2]
    x += __int_as_float(t);
    t = __builtin_amdgcn_update_dpp(0, __float_as_int(x), 0x4E,  0xF, 0xF, true); // quad_perm [2,3,0,1]
    x += __int_as_float(t);
    t = __builtin_amdgcn_update_dpp(0, __float_as_int(x), 0x125, 0xF, 0xF, true); // row_ror:4
    x += __int_as_float(t);
    t = __builtin_amdgcn_update_dpp(0, __float_as_int(x), 0x129, 0xF, 0xF, true); // row_ror:8
    x += __int_as_float(t);
    return x;
}

// async 16B global->LDS
__device__ __forceinline__ void load16_lds(const unsigned short* g, unsigned short* l) {
    __builtin_amdgcn_global_load_lds(
        (const __attribute__((address_space(1))) unsigned int*)(uintptr_t)g,
        (__attribute__((address_space(3))) unsigned int*)(uintptr_t)l,
        16, 0, 0);
}

// h1g LDS addressing: stride 128 shorts, XOR swizzle to spread banks.
__device__ __forceinline__ int hofs(int row, int col) {
    return row * 128 + (col ^ (((row >> 2) & 3) << 4));
}

// ---------------- fused prep ----------------
// blocks 0..255: LDS-tiled weight convert+swizzle (64 W1 | 64 Wr | 128 W2-halves)
// block 256: softmax + rbf coeffs + folded head bias
// blocks 257..288: LN param pack
__global__ void __launch_bounds__(256) prep_all(
    const float* __restrict__ att, const float* __restrict__ log_widths,
    const float* __restrict__ centers, const float* __restrict__ br,
    const float* __restrict__ bias,
    const float* __restrict__ W1, const float* __restrict__ Wr, const float* __restrict__ W2,
    const float* __restrict__ b1, const float* __restrict__ g1, const float* __restrict__ be1,
    const float* __restrict__ b2, const float* __restrict__ g2, const float* __restrict__ be2,
    unsigned short* __restrict__ W1s, unsigned short* __restrict__ Wrs,
    unsigned short* __restrict__ W2s,
    float* __restrict__ wsoft, float* __restrict__ crw2, float* __restrict__ rbias,
    float* __restrict__ Pk)
{
    const int bid = blockIdx.x;
    const int t   = threadIdx.x;

    if (bid < 256) {
        // ---- tiled swizzle: 64 K-rows x 128 cols fp32 -> MFMA B-frag bf16 ----
        __shared__ unsigned int tile32[4096];   // bf16 tile [64][128] as u32 pairs
        const float* src; unsigned short* dst; int KB, kbase;
        if (bid < 64)       { src = W1 + (size_t)bid * 8192;        dst = W1s + (size_t)bid * 8192;        KB = 8;  kbase = 0; }
        else if (bid < 128) { src = Wr + (size_t)(bid - 64) * 8192; dst = Wrs + (size_t)(bid - 64) * 8192; KB = 8;  kbase = 0; }
        else {
            const int u = bid - 128, f = u >> 1, half = u & 1;
            src = W2 + ((size_t)f * 128 + half * 64) * 128;
            dst = W2s + (size_t)f * 16384;
            KB = 16; kbase = half * 8;
        }
        const float4* src4 = (const float4*)src;
#pragma unroll
        for (int i = 0; i < 8; ++i) {
            const int idx = t + i * 256;            // 2048 float4
            const float4 v = src4[idx];
            const unsigned int u0 = (unsigned int)f2bf(v.x) | ((unsigned int)f2bf(v.y) << 16);
            const unsigned int u1 = (unsigned int)f2bf(v.z) | ((unsigned int)f2bf(v.w) << 16);
            tile32[idx * 2]     = u0;
            tile32[idx * 2 + 1] = u1;
        }
        __syncthreads();
        const unsigned short* tile16 = (const unsigned short*)tile32;
#pragma unroll
        for (int i = 0; i < 4; ++i) {
            const int u  = t + i * 256;             // 1024 frag units
            const int nn = u & 15;
            const int kb = (u >> 4) & 7;
            const int nt = u >> 7;
            s16x8 o;
#pragma unroll
            for (int j = 0; j < 8; ++j)
                o[j] = (short)tile16[(kb * 8 + j) * 128 + nt * 16 + nn];
            *(s16x8*)(dst + ((size_t)((nt * KB + kbase + kb) * 16 + nn)) * 8) = o;
        }
    } else if (bid == 256) {
        // ---- softmax + rbf coeffs + folded head bias ----
        __shared__ float ws[64];
        if (t < 64) {
            float v = att[t];
            float m = v;
#pragma unroll
            for (int s = 32; s >= 1; s >>= 1) m = fmaxf(m, __shfl_xor(m, s, 64));
            float e = expf(v - m);
            float ssum = e;
#pragma unroll
            for (int s = 32; s >= 1; s >>= 1) ssum += __shfl_xor(ssum, s, 64);
            const float w = e / ssum;
            ws[t] = w;
            wsoft[t] = w;
        }
        __syncthreads();
        for (int i = t; i < FQ * NBQ; i += 256) {
            float lw = fminf(fmaxf(log_widths[i], -5.0f), 5.0f);
            const float rw = 1.0f / (expf(lw) + 0.1f);
            ((float2*)crw2)[i] = make_float2(rw, -centers[i] * rw);
        }
        if (t < HD) {
            float s = bias[t];
            for (int f = 0; f < FQ; ++f) s += 0.1f * ws[f] * br[f * HD + t];
            rbias[t] = s;
        }
    } else {
        // ---- pack LN params: Pk[(f*128+c)*8] = {b1,g1,be1,0, b2,g2,be2,0} ----
        const int id = (bid - 257) * 256 + t;
        if (id < FQ * HD) {
            ((float4*)Pk)[id * 2]     = make_float4(b1[id], g1[id], be1[id], 0.0f);
            ((float4*)Pk)[id * 2 + 1] = make_float4(b2[id], g2[id], be2[id], 0.0f);
        }
    }
}

// ---------------- fused MFMA NAM body ----------------
// grid 512 = 4 fgroups x 128 row-tiles (M=128). 512 threads = 8 waves, 16 rows/wave.
// Two 32KB LDS regions rotate per iter:
//   W (=region ff&1):  W1r(f) [B1..B2], then W2(f) [B2-DMA .. GEMM2]
//   H (=region ~ff&1): h1g(f) [LN1..GEMM2], then W1r(f+1) DMA [B4 .. next B1]
// DMA cover: W2 under LN1 (~1.2K cyc); W1r under LN2+rbf (~1.2K cyc).
// NOTHING except acc/hc lives across a barrier -> no spills (R6's failure mode).
__global__ void __launch_bounds__(NT, 4) nam_main(
    const float* __restrict__ crw2,
    const float* __restrict__ x,
    const unsigned short* __restrict__ W1s,
    const unsigned short* __restrict__ Wrs,
    const unsigned short* __restrict__ W2s,
    const float* __restrict__ Pk,
    const float* __restrict__ wsoft,
    float* __restrict__ aggP)
{
    __shared__ __align__(16) unsigned short lds[32768];   // 64 KB total

    const int t    = threadIdx.x;
    const int ln   = t & 63;
    const int wv   = t >> 6;        // wave 0..7
    const int n    = ln & 15;
    const int q    = ln >> 4;
    const int wrow = wv * 16;
    const int fg   = blockIdx.x & 3;
    const int rb   = blockIdx.x >> 2;     // 0..127
    const int b0   = rb * MT;

    f32x4 acc[8];
#pragma unroll
    for (int nt = 0; nt < 8; ++nt) acc[nt] = f32x4{0.f, 0.f, 0.f, 0.f};

    // ---- preamble: DMA first feature's W1+Wr into region 0 ----
    {
        const int f0 = fg * FPG + (rb & (FPG - 1));
        const unsigned short* gw1 = W1s + (size_t)f0 * 8192;
        const unsigned short* gwr = Wrs + (size_t)f0 * 8192;
#pragma unroll
        for (int i = 0; i < 4; ++i) {
            const int chunk = i * 8 + wv;
            const unsigned short* src = (chunk < 16) ? (gw1 + chunk * 512)
                                                     : (gwr + (chunk - 16) * 512);
            load16_lds(src + ln * 8, lds + chunk * 512);
        }
    }

    for (int ff = 0; ff < FPG; ++ff) {
        const int f = fg * FPG + ((ff + rb) & (FPG - 1));   // decorrelated order
        unsigned short* W = lds + ((ff & 1) << 14);
        unsigned short* H = lds + (((ff & 1) ^ 1) << 14);

        // ---- rbf A-fragments directly in registers ----
        s16x8 a0, a1;
        {
            float xv = x[(size_t)(b0 + wrow + n) * FQ + f];
            xv = fminf(fmaxf(xv, -10.0f), 10.0f);
            const float4* c4 = ((const float4*)crw2) + f * 32;
            unsigned int p[8];
#pragma unroll
            for (int h = 0; h < 2; ++h) {
#pragma unroll
                for (int i = 0; i < 4; ++i) {
                    const float4 cc = c4[h * 16 + q * 4 + i];   // {rw,nc, rw,nc}
                    const float d0 = fmaf(xv, cc.x, cc.y);
                    const float d1 = fmaf(xv, cc.z, cc.w);
                    const float e0 = __expf(-0.5f * d0 * d0);
                    const float e1 = __expf(-0.5f * d1 * d1);
                    p[h * 4 + i] = __builtin_amdgcn_perm(__float_as_uint(e1),
                                                         __float_as_uint(e0), 0x07060302u);
                }
            }
            int4 pa = make_int4(p[0], p[1], p[2], p[3]);
            int4 pb = make_int4(p[4], p[5], p[6], p[7]);
            a0 = *(s16x8*)&pa;
            a1 = *(s16x8*)&pb;
        }
        const float wf   = wsoft[f];
        const float wf01 = 0.1f * wf;
        __syncthreads();   // B1: W1r(f) ready in W (DMA covered by prev LN2+rbf)

        // ---- GEMM1 (hc) + GEMMr folded straight into acc ----
        f32x4 hc[8];
#pragma unroll
        for (int nt = 0; nt < 8; ++nt) {
            const s16x8 bA = *(const s16x8*)&W[(nt * 8 + 0) * 128 + ln * 8];
            const s16x8 bB = *(const s16x8*)&W[(nt * 8 + 4) * 128 + ln * 8];
            f32x4 z = f32x4{0.f, 0.f, 0.f, 0.f};
            z = __builtin_amdgcn_mfma_f32_16x16x32_bf16(a0, bA, z, 0, 0, 0);
            z = __builtin_amdgcn_mfma_f32_16x16x32_bf16(a1, bB, z, 0, 0, 0);
            hc[nt] = z;
            const s16x8 cA = *(const s16x8*)&W[8192 + (nt * 8 + 0) * 128 + ln * 8];
            const s16x8 cB = *(const s16x8*)&W[8192 + (nt * 8 + 4) * 128 + ln * 8];
            f32x4 y = f32x4{0.f, 0.f, 0.f, 0.f};
            y = __builtin_amdgcn_mfma_f32_16x16x32_bf16(a0, cA, y, 0, 0, 0);
            y = __builtin_amdgcn_mfma_f32_16x16x32_bf16(a1, cB, y, 0, 0, 0);
            acc[nt] = y * wf01 + acc[nt];
        }
        __syncthreads();   // B2: all waves done reading W1r from W

        // ---- stage W2(f) -> W, covered by LN1 below ----
        {
            const unsigned short* gw2 = W2s + (size_t)f * 16384;
#pragma unroll
            for (int i = 0; i < 4; ++i) {
                const int chunk = i * 8 + wv;
                load16_lds(gw2 + chunk * 512 + ln * 8, W + chunk * 512);
            }
        }

        // ---- LN1 (+b1), DPP reduce, gelu, h1g -> H ----
        const size_t pkb = ((size_t)f * HD + n) * 8;
        f32x4 sm = {0.f, 0.f, 0.f, 0.f}, sq = {0.f, 0.f, 0.f, 0.f};
#pragma unroll
        for (int nt = 0; nt < 8; ++nt) {
            const float4 pA = *(const float4*)(Pk + pkb + nt * 128);
            const f32x4 v = hc[nt] + pA.x;
            hc[nt] = v; sm += v; sq += v * v;
        }
        f32x4 mu4, rs4;
#pragma unroll
        for (int i = 0; i < 4; ++i) {
            const float s  = dppsum16(sm[i]);
            const float qq = dppsum16(sq[i]);
            mu4[i] = s * (1.0f / 128.0f);
            const float var = qq * (1.0f / 128.0f) - mu4[i] * mu4[i];
            rs4[i] = rsqrtf(var + 1e-5f);
        }
#pragma unroll
        for (int nt = 0; nt < 8; ++nt) {
            const float4 pA = *(const float4*)(Pk + pkb + nt * 128);
            const f32x4 sg = rs4 * pA.y;
            const f32x4 c1 = -mu4 * sg + pA.z;
            const f32x4 z  = gelu4(hc[nt] * sg + c1);
#pragma unroll
            for (int i = 0; i < 4; ++i)
                H[hofs(wrow + q * 4 + i, nt * 16 + n)] = bftr(z[i]);
        }
        __syncthreads();   // B3: h1g visible + W2 drained (covered by LN1)

        // ---- GEMM2: A-frags read here, die inside the loop (not held across barriers) ----
        {
            s16x8 A2[4];
#pragma unroll
            for (int c = 0; c < 4; ++c)
                A2[c] = *(const s16x8*)&H[hofs(wrow + n, c * 32 + q * 8)];
#pragma unroll
            for (int nt = 0; nt < 8; ++nt) {
                f32x4 z = f32x4{0.f, 0.f, 0.f, 0.f};
#pragma unroll
                for (int c = 0; c < 4; ++c) {
                    const s16x8 bF = *(const s16x8*)&W[(nt * 16 + c * 4) * 128 + ln * 8];
                    z = __builtin_amdgcn_mfma_f32_16x16x32_bf16(A2[c], bF, z, 0, 0, 0);
                }
                hc[nt] = z;
            }
        }
        __syncthreads();   // B4: all waves done reading H (h1g) and W (W2)

        // ---- stage W1r(f+1) -> H, covered by LN2 + next rbf ----
        if (ff + 1 < FPG) {
            const int f2 = fg * FPG + ((ff + 1 + rb) & (FPG - 1));
            const unsigned short* gw1 = W1s + (size_t)f2 * 8192;
            const unsigned short* gwr = Wrs + (size_t)f2 * 8192;
#pragma unroll
            for (int i = 0; i < 4; ++i) {
                const int chunk = i * 8 + wv;
                const unsigned short* src = (chunk < 16) ? (gw1 + chunk * 512)
                                                         : (gwr + (chunk - 16) * 512);
                load16_lds(src + ln * 8, H + chunk * 512);
            }
        }

        // ---- LN2 (+b2), gelu, attention weight into acc ----
        f32x4 sm2 = {0.f, 0.f, 0.f, 0.f}, sq2 = {0.f, 0.f, 0.f, 0.f};
#pragma unroll
        for (int nt = 0; nt < 8; ++nt) {
            const float4 pB = *(const float4*)(Pk + pkb + nt * 128 + 4);
            const f32x4 v = hc[nt] + pB.x;
            hc[nt] = v; sm2 += v; sq2 += v * v;
        }
#pragma unroll
        for (int i = 0; i < 4; ++i) {
            const float s  = dppsum16(sm2[i]);
            const float qq = dppsum16(sq2[i]);
            mu4[i] = s * (1.0f / 128.0f);
            const float var = qq * (1.0f / 128.0f) - mu4[i] * mu4[i];
            rs4[i] = rsqrtf(var + 1e-5f);
        }
#pragma unroll
        for (int nt = 0; nt < 8; ++nt) {
            const float4 pB = *(const float4*)(Pk + pkb + nt * 128 + 4);
            const f32x4 sg = rs4 * pB.y;
            const f32x4 c1 = -mu4 * sg + pB.z;
            acc[nt] = gelu4(hc[nt] * sg + c1) * wf + acc[nt];
        }
        // next B1 orders the W1r(f+1) DMA vs its readers
    }

    // ---- epilogue: plain stores into this fgroup's partial (no atomics) ----
    float* ap = aggP + ((size_t)fg * BQ + b0 + wrow + q * 4) * HD + n;
#pragma unroll
    for (int nt = 0; nt < 8; ++nt) {
#pragma unroll
        for (int i = 0; i < 4; ++i) {
            ap[(size_t)i * HD + nt * 16] = acc[nt][i];
        }
    }
}

// ---------------- mixture-beta head: one wave per batch row ----------------
__global__ void __launch_bounds__(256) nam_head(
    const float* __restrict__ aggP, const float* __restrict__ rbias,
    const float* __restrict__ Wpi, const float* __restrict__ bpi,
    const float* __restrict__ Wa,  const float* __restrict__ ba,
    const float* __restrict__ Wb,  const float* __restrict__ bb,
    float* __restrict__ out)
{
    const int gid  = blockIdx.x * blockDim.x + threadIdx.x;
    const int row  = gid >> 6;
    const int lane = threadIdx.x & 63;
    if (row >= BQ) return;

    const float2 p0 = ((const float2*)(aggP + (size_t)row * HD))[lane];
    const float2 p1 = ((const float2*)(aggP + ((size_t)BQ + row) * HD))[lane];
    const float2 p2 = ((const float2*)(aggP + ((size_t)2 * BQ + row) * HD))[lane];
    const float2 p3 = ((const float2*)(aggP + ((size_t)3 * BQ + row) * HD))[lane];
    const float2 rb = ((const float2*)rbias)[lane];
    const float ax = p0.x + p1.x + p2.x + p3.x + rb.x;
    const float ay = p0.y + p1.y + p2.y + p3.y + rb.y;

    const float2* wp = (const float2*)Wpi;
    const float2* wa = (const float2*)Wa;
    const float2* wb = (const float2*)Wb;
    const float2 p01 = wp[lane * 3], p23 = wp[lane * 3 + 1], p45 = wp[lane * 3 + 2];
    const float2 a01 = wa[lane * 3], a23 = wa[lane * 3 + 1], a45 = wa[lane * 3 + 2];
    const float2 b01 = wb[lane * 3], b23 = wb[lane * 3 + 1], b45 = wb[lane * 3 + 2];

    float ppi0 = ax * p01.x + ay * p23.y;
    float ppi1 = ax * p01.y + ay * p45.x;
    float ppi2 = ax * p23.x + ay * p45.y;
    float pa0  = ax * a01.x + ay * a23.y;
    float pa1  = ax * a01.y + ay * a45.x;
    float pa2  = ax * a23.x + ay * a45.y;
    float pb0  = ax * b01.x + ay * b23.y;
    float pb1  = ax * b01.y + ay * b45.x;
    float pb2  = ax * b23.x + ay * b45.y;

#pragma unroll
    for (int s = 32; s >= 1; s >>= 1) {
        ppi0 += __shfl_xor(ppi0, s, 64);
        ppi1 += __shfl_xor(ppi1, s, 64);
        ppi2 += __shfl_xor(ppi2, s, 64);
        pa0  += __shfl_xor(pa0,  s, 64);
        pa1  += __shfl_xor(pa1,  s, 64);
        pa2  += __shfl_xor(pa2,  s, 64);
        pb0  += __shfl_xor(pb0,  s, 64);
        pb1  += __shfl_xor(pb1,  s, 64);
        pb2  += __shfl_xor(pb2,  s, 64);
    }

    if (lane == 0) {
        const float z0 = ppi0 + bpi[0], z1 = ppi1 + bpi[1], z2 = ppi2 + bpi[2];
        const float mz = fmaxf(z0, fmaxf(z1, z2));
        const float e0 = expf(z0 - mz), e1 = expf(z1 - mz), e2 = expf(z2 - mz);
        const float es = e0 + e1 + e2;

        const float al0 = fminf(fmaxf(softplus_stable(pa0 + ba[0]) + 1.01f, 1.01f), 100.0f);
        const float al1 = fminf(fmaxf(softplus_stable(pa1 + ba[1]) + 1.01f, 1.01f), 100.0f);
        const float al2 = fminf(fmaxf(softplus_stable(pa2 + ba[2]) + 1.01f, 1.01f), 100.0f);
        const float bt0 = fminf(fmaxf(softplus_stable(pb0 + bb[0]) + 1.01f, 1.01f), 100.0f);
        const float bt1 = fminf(fmaxf(softplus_stable(pb1 + bb[1]) + 1.01f, 1.01f), 100.0f);
        const float bt2 = fminf(fmaxf(softplus_stable(pb2 + bb[2]) + 1.01f, 1.01f), 100.0f);

        const float pred = (e0 * (al0 / (al0 + bt0))
                          + e1 * (al1 / (al1 + bt1))
                          + e2 * (al2 / (al2 + bt2))) / es;
        out[row] = fminf(fmaxf(pred, 0.001f), 0.999f);
    }
}

extern "C" void kernel_launch(void* const* d_in, const int* in_sizes, int n_in,
                              void* d_out, int out_size, void* d_ws, size_t ws_size,
                              hipStream_t stream) {
    const float* x          = (const float*)d_in[0];
    const float* centers    = (const float*)d_in[1];
    const float* log_widths = (const float*)d_in[2];
    const float* W1   = (const float*)d_in[3];
    const float* b1   = (const float*)d_in[4];
    const float* g1   = (const float*)d_in[5];
    const float* be1  = (const float*)d_in[6];
    const float* W2   = (const float*)d_in[7];
    const float* b2   = (const float*)d_in[8];
    const float* g2   = (const float*)d_in[9];
    const float* be2  = (const float*)d_in[10];
    const float* Wr   = (const float*)d_in[11];
    const float* br   = (const float*)d_in[12];
    const float* att  = (const float*)d_in[13];
    const float* bias = (const float*)d_in[14];
    const float* Wpi  = (const float*)d_in[15];
    const float* bpi  = (const float*)d_in[16];
    const float* Wa   = (const float*)d_in[17];
    const float* ba   = (const float*)d_in[18];
    const float* Wb   = (const float*)d_in[19];
    const float* bb   = (const float*)d_in[20];

    // ---- workspace layout (byte offsets, 16B-aligned; top ≈ 36.5 MB) ----
    char* ws = (char*)d_ws;
    float*          wsoft = (float*)(ws + 0);          //   256 B
    float*          rbias = (float*)(ws + 1024);       //   512 B
    float*          crw2  = (float*)(ws + 8192);       //  32 KB (float2[4096])
    float*          Pk    = (float*)(ws + 65536);      // 256 KB
    unsigned short* W1s   = (unsigned short*)(ws + 327680);    // 1 MB
    unsigned short* Wrs   = (unsigned short*)(ws + 1376256);   // 1 MB
    unsigned short* W2s   = (unsigned short*)(ws + 2424832);   // 2 MB
    float*          aggP  = (float*)(ws + 4521984);    //  32 MB (4 partials)

    prep_all<<<289, 256, 0, stream>>>(att, log_widths, centers, br, bias,
                                      W1, Wr, W2, b1, g1, be1, b2, g2, be2,
                                      W1s, Wrs, W2s, wsoft, crw2, rbias, Pk);

    nam_main<<<(BQ / MT) * FG, NT, 0, stream>>>(crw2, x, W1s, Wrs, W2s, Pk,
                                                wsoft, aggP);

    nam_head<<<BQ / 4, 256, 0, stream>>>(aggP, rbias, Wpi, bpi, Wa, ba, Wb, bb,
                                         (float*)d_out);
}

// Round 8
// 445.685 us; speedup vs baseline: 1.2482x; 1.2270x over previous
//
#include <hip/hip_runtime.h>
#include <math.h>

// Problem constants (fixed by the reference).
#define BQ   16384
#define FQ   64
#define NBQ  64
#define HD   128
#define FG   4       // feature groups
#define FPG  16      // features per group
#define MT   128     // batch rows per block
#define NT   512     // threads (8 waves)

typedef __attribute__((ext_vector_type(8))) short s16x8;   // 8 bf16 (4 VGPRs)
typedef __attribute__((ext_vector_type(4))) float f32x4;   // MFMA C/D

// round-to-nearest-even fp32 -> bf16 (weight prep only)
__device__ __forceinline__ unsigned short f2bf(float x) {
    unsigned int u = __float_as_uint(x);
    return (unsigned short)((u + 0x7FFFu + ((u >> 16) & 1u)) >> 16);
}
// truncation fp32 -> bf16 (activations)
__device__ __forceinline__ unsigned short bftr(float x) {
    return (unsigned short)(__float_as_uint(x) >> 16);
}

__device__ __forceinline__ float softplus_stable(float v) {
    return (v > 0.0f) ? (v + log1pf(expf(-v))) : log1pf(expf(v));
}

// tanh-form gelu as sigmoid: gelu(v) = v / (1 + exp(-(1.5957691 v + 0.07135481 v^3)))
__device__ __forceinline__ f32x4 gelu4(f32x4 v) {
    const f32x4 v2 = v * v;
    const f32x4 tt = v2 * (-0.07135481f) + (-1.5957691f);
    const f32x4 s  = v * tt;
    f32x4 r;
    r[0] = __fdividef(v[0], 1.0f + __expf(s[0]));
    r[1] = __fdividef(v[1], 1.0f + __expf(s[1]));
    r[2] = __fdividef(v[2], 1.0f + __expf(s[2]));
    r[3] = __fdividef(v[3], 1.0f + __expf(s[3]));
    return r;
}

// sum across the 16 lanes of a DPP row — no LDS ops.
__device__ __forceinline__ float dppsum16(float x) {
    int t;
    t = __builtin_amdgcn_update_dpp(0, __float_as_int(x), 0xB1,  0xF, 0xF, true); // quad_perm [1,0,3,2]
    x += __int_as_float(t);
    t = __builtin_amdgcn_update_dpp(0, __float_as_int(x), 0x4E,  0xF, 0xF, true); // quad_perm [2,3,0,1]
    x += __int_as_float(t);
    t = __builtin_amdgcn_update_dpp(0, __float_as_int(x), 0x125, 0xF, 0xF, true); // row_ror:4
    x += __int_as_float(t);
    t = __builtin_amdgcn_update_dpp(0, __float_as_int(x), 0x129, 0xF, 0xF, true); // row_ror:8
    x += __int_as_float(t);
    return x;
}

// async 16B global->LDS
__device__ __forceinline__ void load16_lds(const unsigned short* g, unsigned short* l) {
    __builtin_amdgcn_global_load_lds(
        (const __attribute__((address_space(1))) unsigned int*)(uintptr_t)g,
        (__attribute__((address_space(3))) unsigned int*)(uintptr_t)l,
        16, 0, 0);
}

// h1g LDS addressing: stride 128 shorts, XOR swizzle to spread banks.
__device__ __forceinline__ int hofs(int row, int col) {
    return row * 128 + (col ^ (((row >> 2) & 3) << 4));
}

// ---------------- fused prep ----------------
// blocks 0..255: LDS-tiled weight convert+swizzle (64 W1 | 64 Wr | 128 W2-halves)
// block 256: softmax + rbf coeffs + folded head bias
// blocks 257..288: LN param pack
__global__ void __launch_bounds__(256) prep_all(
    const float* __restrict__ att, const float* __restrict__ log_widths,
    const float* __restrict__ centers, const float* __restrict__ br,
    const float* __restrict__ bias,
    const float* __restrict__ W1, const float* __restrict__ Wr, const float* __restrict__ W2,
    const float* __restrict__ b1, const float* __restrict__ g1, const float* __restrict__ be1,
    const float* __restrict__ b2, const float* __restrict__ g2, const float* __restrict__ be2,
    unsigned short* __restrict__ W1s, unsigned short* __restrict__ Wrs,
    unsigned short* __restrict__ W2s,
    float* __restrict__ wsoft, float* __restrict__ crw2, float* __restrict__ rbias,
    float* __restrict__ Pk)
{
    const int bid = blockIdx.x;
    const int t   = threadIdx.x;

    if (bid < 256) {
        // ---- tiled swizzle: 64 K-rows x 128 cols fp32 -> MFMA B-frag bf16 ----
        __shared__ unsigned int tile32[4096];   // bf16 tile [64][128] as u32 pairs
        const float* src; unsigned short* dst; int KB, kbase;
        if (bid < 64)       { src = W1 + (size_t)bid * 8192;        dst = W1s + (size_t)bid * 8192;        KB = 8;  kbase = 0; }
        else if (bid < 128) { src = Wr + (size_t)(bid - 64) * 8192; dst = Wrs + (size_t)(bid - 64) * 8192; KB = 8;  kbase = 0; }
        else {
            const int u = bid - 128, f = u >> 1, half = u & 1;
            src = W2 + ((size_t)f * 128 + half * 64) * 128;
            dst = W2s + (size_t)f * 16384;
            KB = 16; kbase = half * 8;
        }
        const float4* src4 = (const float4*)src;
#pragma unroll
        for (int i = 0; i < 8; ++i) {
            const int idx = t + i * 256;            // 2048 float4
            const float4 v = src4[idx];
            const unsigned int u0 = (unsigned int)f2bf(v.x) | ((unsigned int)f2bf(v.y) << 16);
            const unsigned int u1 = (unsigned int)f2bf(v.z) | ((unsigned int)f2bf(v.w) << 16);
            tile32[idx * 2]     = u0;
            tile32[idx * 2 + 1] = u1;
        }
        __syncthreads();
        const unsigned short* tile16 = (const unsigned short*)tile32;
#pragma unroll
        for (int i = 0; i < 4; ++i) {
            const int u  = t + i * 256;             // 1024 frag units
            const int nn = u & 15;
            const int kb = (u >> 4) & 7;
            const int nt = u >> 7;
            s16x8 o;
#pragma unroll
            for (int j = 0; j < 8; ++j)
                o[j] = (short)tile16[(kb * 8 + j) * 128 + nt * 16 + nn];
            *(s16x8*)(dst + ((size_t)((nt * KB + kbase + kb) * 16 + nn)) * 8) = o;
        }
    } else if (bid == 256) {
        // ---- softmax + rbf coeffs + folded head bias ----
        __shared__ float ws[64];
        if (t < 64) {
            float v = att[t];
            float m = v;
#pragma unroll
            for (int s = 32; s >= 1; s >>= 1) m = fmaxf(m, __shfl_xor(m, s, 64));
            float e = expf(v - m);
            float ssum = e;
#pragma unroll
            for (int s = 32; s >= 1; s >>= 1) ssum += __shfl_xor(ssum, s, 64);
            const float w = e / ssum;
            ws[t] = w;
            wsoft[t] = w;
        }
        __syncthreads();
        for (int i = t; i < FQ * NBQ; i += 256) {
            float lw = fminf(fmaxf(log_widths[i], -5.0f), 5.0f);
            const float rw = 1.0f / (expf(lw) + 0.1f);
            ((float2*)crw2)[i] = make_float2(rw, -centers[i] * rw);
        }
        if (t < HD) {
            float s = bias[t];
            for (int f = 0; f < FQ; ++f) s += 0.1f * ws[f] * br[f * HD + t];
            rbias[t] = s;
        }
    } else {
        // ---- pack LN params: Pk[(f*128+c)*8] = {b1,g1,be1,0, b2,g2,be2,0} ----
        const int id = (bid - 257) * 256 + t;
        if (id < FQ * HD) {
            ((float4*)Pk)[id * 2]     = make_float4(b1[id], g1[id], be1[id], 0.0f);
            ((float4*)Pk)[id * 2 + 1] = make_float4(b2[id], g2[id], be2[id], 0.0f);
        }
    }
}

// ---------------- fused MFMA NAM body (R4 structure — the no-spill reference) ----
// grid 512 = 4 fgroups x 128 row-tiles (M=128). 512 threads = 8 waves, 16 rows/wave.
// LDS 64 KB (wbuf + hbuf, FIXED roles) -> 2 blocks/CU.
// Barriers: B0 top | B1 drains W1r DMA | B2 frees wbuf | B3 drains W2 + h1g.
__global__ void __launch_bounds__(NT, 4) nam_main(
    const float* __restrict__ crw2,
    const float* __restrict__ x,
    const unsigned short* __restrict__ W1s,
    const unsigned short* __restrict__ Wrs,
    const unsigned short* __restrict__ W2s,
    const float* __restrict__ Pk,
    const float* __restrict__ wsoft,
    float* __restrict__ aggP)
{
    __shared__ __align__(16) unsigned short wbuf[16384];   // 32 KB: W1+Wr, then W2
    __shared__ __align__(16) unsigned short hbuf[16384];   // 32 KB: h1g (swizzled)

    const int t    = threadIdx.x;
    const int ln   = t & 63;
    const int wv   = t >> 6;        // wave 0..7
    const int n    = ln & 15;
    const int q    = ln >> 4;
    const int wrow = wv * 16;
    const int fg   = blockIdx.x & 3;
    const int rb   = blockIdx.x >> 2;     // 0..127
    const int b0   = rb * MT;

    f32x4 acc[8];
#pragma unroll
    for (int nt = 0; nt < 8; ++nt) acc[nt] = f32x4{0.f, 0.f, 0.f, 0.f};

    for (int ff = 0; ff < FPG; ++ff) {
        const int f = fg * FPG + ((ff + rb) & (FPG - 1));   // decorrelated order
        __syncthreads();   // B0: prev iter's wbuf(W2)/hbuf(h1g) readers done

        // ---- stage W1[f]+Wr[f] (32 KB) async into wbuf ----
        {
            const unsigned short* gw1 = W1s + (size_t)f * 8192;
            const unsigned short* gwr = Wrs + (size_t)f * 8192;
#pragma unroll
            for (int i = 0; i < 4; ++i) {
                const int chunk = i * 8 + wv;   // 32 x 1KB chunks
                const unsigned short* src = (chunk < 16) ? (gw1 + chunk * 512)
                                                         : (gwr + (chunk - 16) * 512);
                load16_lds(src + ln * 8, wbuf + chunk * 512);
            }
        }

        // ---- rbf A-fragments directly in registers (x read: same 64B line all iters) ----
        s16x8 a0, a1;
        {
            float xv = x[(size_t)(b0 + wrow + n) * FQ + f];
            xv = fminf(fmaxf(xv, -10.0f), 10.0f);
            const float4* c4 = ((const float4*)crw2) + f * 32;
            unsigned int p[8];
#pragma unroll
            for (int h = 0; h < 2; ++h) {
#pragma unroll
                for (int i = 0; i < 4; ++i) {
                    const float4 cc = c4[h * 16 + q * 4 + i];   // {rw,nc, rw,nc}
                    const float d0 = fmaf(xv, cc.x, cc.y);
                    const float d1 = fmaf(xv, cc.z, cc.w);
                    const float e0 = __expf(-0.5f * d0 * d0);
                    const float e1 = __expf(-0.5f * d1 * d1);
                    p[h * 4 + i] = __builtin_amdgcn_perm(__float_as_uint(e1),
                                                         __float_as_uint(e0), 0x07060302u);
                }
            }
            int4 pa = make_int4(p[0], p[1], p[2], p[3]);
            int4 pb = make_int4(p[4], p[5], p[6], p[7]);
            a0 = *(s16x8*)&pa;
            a1 = *(s16x8*)&pb;
        }
        const float wf   = wsoft[f];
        const float wf01 = 0.1f * wf;
        __syncthreads();   // B1: W1r DMA drained, W1/Wr visible

        // ---- GEMM1 (hc) + GEMMr folded straight into acc ----
        f32x4 hc[8];
#pragma unroll
        for (int nt = 0; nt < 8; ++nt) {
            const s16x8 bA = *(const s16x8*)&wbuf[(nt * 8 + 0) * 128 + ln * 8];
            const s16x8 bB = *(const s16x8*)&wbuf[(nt * 8 + 4) * 128 + ln * 8];
            f32x4 z = f32x4{0.f, 0.f, 0.f, 0.f};
            z = __builtin_amdgcn_mfma_f32_16x16x32_bf16(a0, bA, z, 0, 0, 0);
            z = __builtin_amdgcn_mfma_f32_16x16x32_bf16(a1, bB, z, 0, 0, 0);
            hc[nt] = z;
            const s16x8 cA = *(const s16x8*)&wbuf[8192 + (nt * 8 + 0) * 128 + ln * 8];
            const s16x8 cB = *(const s16x8*)&wbuf[8192 + (nt * 8 + 4) * 128 + ln * 8];
            f32x4 y = f32x4{0.f, 0.f, 0.f, 0.f};
            y = __builtin_amdgcn_mfma_f32_16x16x32_bf16(a0, cA, y, 0, 0, 0);
            y = __builtin_amdgcn_mfma_f32_16x16x32_bf16(a1, cB, y, 0, 0, 0);
            acc[nt] = y * wf01 + acc[nt];
        }
        __syncthreads();   // B2: all waves done reading W1/Wr

        // ---- stage W2[f] (32 KB) async — covered by LN1 VALU below ----
        {
            const unsigned short* gw2 = W2s + (size_t)f * 16384;
#pragma unroll
            for (int i = 0; i < 4; ++i) {
                const int chunk = i * 8 + wv;
                load16_lds(gw2 + chunk * 512 + ln * 8, wbuf + chunk * 512);
            }
        }

        // ---- LN1 (+b1), DPP reduce, gelu, h1g -> hbuf ----
        const size_t pkb = ((size_t)f * HD + n) * 8;
        f32x4 sm = {0.f, 0.f, 0.f, 0.f}, sq = {0.f, 0.f, 0.f, 0.f};
#pragma unroll
        for (int nt = 0; nt < 8; ++nt) {
            const float4 pA = *(const float4*)(Pk + pkb + nt * 128);
            const f32x4 v = hc[nt] + pA.x;
            hc[nt] = v; sm += v; sq += v * v;
        }
        f32x4 mu4, rs4;
#pragma unroll
        for (int i = 0; i < 4; ++i) {
            const float s  = dppsum16(sm[i]);
            const float qq = dppsum16(sq[i]);
            mu4[i] = s * (1.0f / 128.0f);
            const float var = qq * (1.0f / 128.0f) - mu4[i] * mu4[i];
            rs4[i] = rsqrtf(var + 1e-5f);
        }
#pragma unroll
        for (int nt = 0; nt < 8; ++nt) {
            const float4 pA = *(const float4*)(Pk + pkb + nt * 128);
            const f32x4 sg = rs4 * pA.y;
            const f32x4 c1 = -mu4 * sg + pA.z;
            const f32x4 z  = gelu4(hc[nt] * sg + c1);
#pragma unroll
            for (int i = 0; i < 4; ++i)
                hbuf[hofs(wrow + q * 4 + i, nt * 16 + n)] = bftr(z[i]);
        }
        __syncthreads();   // B3: W2 drained + h1g visible

        // ---- GEMM2: A = h1g frags (K=128); output reuses hc regs ----
        {
            s16x8 A2[4];
#pragma unroll
            for (int c = 0; c < 4; ++c)
                A2[c] = *(const s16x8*)&hbuf[hofs(wrow + n, c * 32 + q * 8)];
#pragma unroll
            for (int nt = 0; nt < 8; ++nt) {
                f32x4 z = f32x4{0.f, 0.f, 0.f, 0.f};
#pragma unroll
                for (int c = 0; c < 4; ++c) {
                    const s16x8 bF = *(const s16x8*)&wbuf[(nt * 16 + c * 4) * 128 + ln * 8];
                    z = __builtin_amdgcn_mfma_f32_16x16x32_bf16(A2[c], bF, z, 0, 0, 0);
                }
                hc[nt] = z;
            }
        }

        // ---- LN2 (+b2), gelu, attention weight into acc ----
        sm = f32x4{0.f, 0.f, 0.f, 0.f}; sq = f32x4{0.f, 0.f, 0.f, 0.f};
#pragma unroll
        for (int nt = 0; nt < 8; ++nt) {
            const float4 pB = *(const float4*)(Pk + pkb + nt * 128 + 4);
            const f32x4 v = hc[nt] + pB.x;
            hc[nt] = v; sm += v; sq += v * v;
        }
#pragma unroll
        for (int i = 0; i < 4; ++i) {
            const float s  = dppsum16(sm[i]);
            const float qq = dppsum16(sq[i]);
            mu4[i] = s * (1.0f / 128.0f);
            const float var = qq * (1.0f / 128.0f) - mu4[i] * mu4[i];
            rs4[i] = rsqrtf(var + 1e-5f);
        }
#pragma unroll
        for (int nt = 0; nt < 8; ++nt) {
            const float4 pB = *(const float4*)(Pk + pkb + nt * 128 + 4);
            const f32x4 sg = rs4 * pB.y;
            const f32x4 c1 = -mu4 * sg + pB.z;
            acc[nt] = gelu4(hc[nt] * sg + c1) * wf + acc[nt];
        }
    }

    // ---- epilogue: plain stores into this fgroup's partial (no atomics) ----
    float* ap = aggP + ((size_t)fg * BQ + b0 + wrow + q * 4) * HD + n;
#pragma unroll
    for (int nt = 0; nt < 8; ++nt) {
#pragma unroll
        for (int i = 0; i < 4; ++i) {
            ap[(size_t)i * HD + nt * 16] = acc[nt][i];
        }
    }
}

// ---------------- mixture-beta head: one wave per batch row ----------------
__global__ void __launch_bounds__(256) nam_head(
    const float* __restrict__ aggP, const float* __restrict__ rbias,
    const float* __restrict__ Wpi, const float* __restrict__ bpi,
    const float* __restrict__ Wa,  const float* __restrict__ ba,
    const float* __restrict__ Wb,  const float* __restrict__ bb,
    float* __restrict__ out)
{
    const int gid  = blockIdx.x * blockDim.x + threadIdx.x;
    const int row  = gid >> 6;
    const int lane = threadIdx.x & 63;
    if (row >= BQ) return;

    const float2 p0 = ((const float2*)(aggP + (size_t)row * HD))[lane];
    const float2 p1 = ((const float2*)(aggP + ((size_t)BQ + row) * HD))[lane];
    const float2 p2 = ((const float2*)(aggP + ((size_t)2 * BQ + row) * HD))[lane];
    const float2 p3 = ((const float2*)(aggP + ((size_t)3 * BQ + row) * HD))[lane];
    const float2 rb = ((const float2*)rbias)[lane];
    const float ax = p0.x + p1.x + p2.x + p3.x + rb.x;
    const float ay = p0.y + p1.y + p2.y + p3.y + rb.y;

    const float2* wp = (const float2*)Wpi;
    const float2* wa = (const float2*)Wa;
    const float2* wb = (const float2*)Wb;
    const float2 p01 = wp[lane * 3], p23 = wp[lane * 3 + 1], p45 = wp[lane * 3 + 2];
    const float2 a01 = wa[lane * 3], a23 = wa[lane * 3 + 1], a45 = wa[lane * 3 + 2];
    const float2 b01 = wb[lane * 3], b23 = wb[lane * 3 + 1], b45 = wb[lane * 3 + 2];

    float ppi0 = ax * p01.x + ay * p23.y;
    float ppi1 = ax * p01.y + ay * p45.x;
    float ppi2 = ax * p23.x + ay * p45.y;
    float pa0  = ax * a01.x + ay * a23.y;
    float pa1  = ax * a01.y + ay * a45.x;
    float pa2  = ax * a23.x + ay * a45.y;
    float pb0  = ax * b01.x + ay * b23.y;
    float pb1  = ax * b01.y + ay * b45.x;
    float pb2  = ax * b23.x + ay * b45.y;

#pragma unroll
    for (int s = 32; s >= 1; s >>= 1) {
        ppi0 += __shfl_xor(ppi0, s, 64);
        ppi1 += __shfl_xor(ppi1, s, 64);
        ppi2 += __shfl_xor(ppi2, s, 64);
        pa0  += __shfl_xor(pa0,  s, 64);
        pa1  += __shfl_xor(pa1,  s, 64);
        pa2  += __shfl_xor(pa2,  s, 64);
        pb0  += __shfl_xor(pb0,  s, 64);
        pb1  += __shfl_xor(pb1,  s, 64);
        pb2  += __shfl_xor(pb2,  s, 64);
    }

    if (lane == 0) {
        const float z0 = ppi0 + bpi[0], z1 = ppi1 + bpi[1], z2 = ppi2 + bpi[2];
        const float mz = fmaxf(z0, fmaxf(z1, z2));
        const float e0 = expf(z0 - mz), e1 = expf(z1 - mz), e2 = expf(z2 - mz);
        const float es = e0 + e1 + e2;

        const float al0 = fminf(fmaxf(softplus_stable(pa0 + ba[0]) + 1.01f, 1.01f), 100.0f);
        const float al1 = fminf(fmaxf(softplus_stable(pa1 + ba[1]) + 1.01f, 1.01f), 100.0f);
        const float al2 = fminf(fmaxf(softplus_stable(pa2 + ba[2]) + 1.01f, 1.01f), 100.0f);
        const float bt0 = fminf(fmaxf(softplus_stable(pb0 + bb[0]) + 1.01f, 1.01f), 100.0f);
        const float bt1 = fminf(fmaxf(softplus_stable(pb1 + bb[1]) + 1.01f, 1.01f), 100.0f);
        const float bt2 = fminf(fmaxf(softplus_stable(pb2 + bb[2]) + 1.01f, 1.01f), 100.0f);

        const float pred = (e0 * (al0 / (al0 + bt0))
                          + e1 * (al1 / (al1 + bt1))
                          + e2 * (al2 / (al2 + bt2))) / es;
        out[row] = fminf(fmaxf(pred, 0.001f), 0.999f);
    }
}

extern "C" void kernel_launch(void* const* d_in, const int* in_sizes, int n_in,
                              void* d_out, int out_size, void* d_ws, size_t ws_size,
                              hipStream_t stream) {
    const float* x          = (const float*)d_in[0];
    const float* centers    = (const float*)d_in[1];
    const float* log_widths = (const float*)d_in[2];
    const float* W1   = (const float*)d_in[3];
    const float* b1   = (const float*)d_in[4];
    const float* g1   = (const float*)d_in[5];
    const float* be1  = (const float*)d_in[6];
    const float* W2   = (const float*)d_in[7];
    const float* b2   = (const float*)d_in[8];
    const float* g2   = (const float*)d_in[9];
    const float* be2  = (const float*)d_in[10];
    const float* Wr   = (const float*)d_in[11];
    const float* br   = (const float*)d_in[12];
    const float* att  = (const float*)d_in[13];
    const float* bias = (const float*)d_in[14];
    const float* Wpi  = (const float*)d_in[15];
    const float* bpi  = (const float*)d_in[16];
    const float* Wa   = (const float*)d_in[17];
    const float* ba   = (const float*)d_in[18];
    const float* Wb   = (const float*)d_in[19];
    const float* bb   = (const float*)d_in[20];

    // ---- workspace layout (byte offsets, 16B-aligned; top ≈ 36.5 MB) ----
    char* ws = (char*)d_ws;
    float*          wsoft = (float*)(ws + 0);          //   256 B
    float*          rbias = (float*)(ws + 1024);       //   512 B
    float*          crw2  = (float*)(ws + 8192);       //  32 KB (float2[4096])
    float*          Pk    = (float*)(ws + 65536);      // 256 KB
    unsigned short* W1s   = (unsigned short*)(ws + 327680);    // 1 MB
    unsigned short* Wrs   = (unsigned short*)(ws + 1376256);   // 1 MB
    unsigned short* W2s   = (unsigned short*)(ws + 2424832);   // 2 MB
    float*          aggP  = (float*)(ws + 4521984);    //  32 MB (4 partials)

    prep_all<<<289, 256, 0, stream>>>(att, log_widths, centers, br, bias,
                                      W1, Wr, W2, b1, g1, be1, b2, g2, be2,
                                      W1s, Wrs, W2s, wsoft, crw2, rbias, Pk);

    nam_main<<<(BQ / MT) * FG, NT, 0, stream>>>(crw2, x, W1s, Wrs, W2s, Pk,
                                                wsoft, aggP);

    nam_head<<<BQ / 4, 256, 0, stream>>>(aggP, rbias, Wpi, bpi, Wa, ba, Wb, bb,
                                         (float*)d_out);
}